// Round 1
// baseline (2927.186 us; speedup 1.0000x reference)
//
#include <hip/hip_runtime.h>

// RNAGNN: 7× GCNConv + 4× BatchNorm/ReLU on N=200k nodes, E=6.4M edges.
// Formulation: y = dinv ⊙ (h @ W);  agg[d] = Σ_{e:dst=d} y[src_e];
//              out[d] = dinv[d]*(agg[d] + y[d]) + b   (self-loop folded in)

#define DIM 16
#define F_IN 64

__global__ void deg_kernel(const int* __restrict__ dst, unsigned* __restrict__ deg, int E) {
    int e = blockIdx.x * blockDim.x + threadIdx.x;
    if (e < E) atomicAdd(&deg[dst[e]], 1u);
}

__global__ void dinv_kernel(float* __restrict__ dinv, int n) {
    int i = blockIdx.x * blockDim.x + threadIdx.x;
    if (i < n) {
        unsigned d = ((const unsigned*)dinv)[i];   // in-place: deg (uint) -> dinv (float)
        dinv[i] = rsqrtf((float)(d + 1u));         // +1 = self loop
    }
}

// y[i][f] = dinv[i] * sum_k x[i][k] * W[k][f]   (F_IN = 64 input features)
__global__ void xw64_kernel(const float* __restrict__ x, const float* __restrict__ W,
                            const float* __restrict__ dinv, float* __restrict__ y, int n) {
    __shared__ float sW[F_IN * DIM];
    int t = threadIdx.x;
    for (int i = t; i < F_IN * DIM; i += blockDim.x) sW[i] = W[i];
    __syncthreads();
    int idx = blockIdx.x * blockDim.x + t;
    if (idx >= n * DIM) return;
    int i = idx >> 4, f = idx & 15;
    const float* xr = x + i * F_IN;
    float acc = 0.f;
#pragma unroll
    for (int k = 0; k < F_IN; ++k) acc += xr[k] * sW[k * DIM + f];
    y[idx] = dinv[i] * acc;
}

// Same for DIM=16 input features
__global__ void xw16_kernel(const float* __restrict__ h, const float* __restrict__ W,
                            const float* __restrict__ dinv, float* __restrict__ y, int n) {
    __shared__ float sW[DIM * DIM];
    int t = threadIdx.x;
    if (t < DIM * DIM) sW[t] = W[t];
    __syncthreads();
    int idx = blockIdx.x * blockDim.x + t;
    if (idx >= n * DIM) return;
    int i = idx >> 4, f = idx & 15;
    const float* hr = h + i * DIM;
    float acc = 0.f;
#pragma unroll
    for (int k = 0; k < DIM; ++k) acc += hr[k] * sW[k * DIM + f];
    y[idx] = dinv[i] * acc;
}

// One thread per (edge, feature): agg[dst][f] += y[src][f]
__global__ void scatter_kernel(const int* __restrict__ src, const int* __restrict__ dst,
                               const float* __restrict__ y, float* __restrict__ agg, int E) {
    int idx = blockIdx.x * blockDim.x + threadIdx.x;   // E*16 = 102.4M < 2^31
    if (idx >= E * DIM) return;
    int e = idx >> 4, f = idx & 15;
    int s = src[e], d = dst[e];
    atomicAdd(&agg[d * DIM + f], y[s * DIM + f]);
}

// out = dinv*(agg + y) + b ; mode 0: plain, 1: also accumulate BN sums, 2: ReLU
__global__ void finalize_kernel(const float* __restrict__ agg, const float* __restrict__ y,
                                const float* __restrict__ dinv, const float* __restrict__ b,
                                float* __restrict__ out, float* __restrict__ bnsum,
                                int n, int mode) {
    __shared__ float sdata[256];
    __shared__ float sdata2[256];
    int t = threadIdx.x;
    float sum = 0.f, sumsq = 0.f;
    int total = n * DIM;
    int stride = gridDim.x * blockDim.x;               // 1024*256: divisible by 16
    for (int idx = blockIdx.x * blockDim.x + t; idx < total; idx += stride) {
        int i = idx >> 4;
        float v = dinv[i] * (agg[idx] + y[idx]) + b[idx & 15];
        if (mode == 2) v = fmaxf(v, 0.f);
        out[idx] = v;
        sum += v; sumsq += v * v;
    }
    if (mode == 1) {
        sdata[t] = sum; sdata2[t] = sumsq;
        __syncthreads();
        for (int s = 128; s >= 16; s >>= 1) {
            if (t < s) { sdata[t] += sdata[t + s]; sdata2[t] += sdata2[t + s]; }
            __syncthreads();
        }
        if (t < 16) {
            atomicAdd(&bnsum[t], sdata[t]);
            atomicAdd(&bnsum[16 + t], sdata2[t]);
        }
    }
}

__global__ void bn_relu_kernel(const float* __restrict__ hp, const float* __restrict__ bnsum,
                               const float* __restrict__ gamma, const float* __restrict__ beta,
                               float* __restrict__ h, int n) {
    int idx = blockIdx.x * blockDim.x + threadIdx.x;
    if (idx >= n * DIM) return;
    int f = idx & 15;
    float invN = 1.f / (float)n;
    float mean = bnsum[f] * invN;
    float var = bnsum[16 + f] * invN - mean * mean;
    var = fmaxf(var, 0.f);
    float v = gamma[f] * (hp[idx] - mean) * rsqrtf(var + 1e-5f) + beta[f];
    h[idx] = fmaxf(v, 0.f);
}

extern "C" void kernel_launch(void* const* d_in, const int* in_sizes, int n_in,
                              void* d_out, int out_size, void* d_ws, size_t ws_size,
                              hipStream_t stream) {
    (void)n_in; (void)out_size; (void)ws_size;
    const float* x      = (const float*)d_in[0];
    const int*   edge   = (const int*)d_in[1];
    const float* W_in   = (const float*)d_in[2];
    const float* b_in   = (const float*)d_in[3];
    const float* Ws     = (const float*)d_in[4];
    const float* bs     = (const float*)d_in[5];
    const float* gammas = (const float*)d_in[6];
    const float* betas  = (const float*)d_in[7];
    const float* W_sin  = (const float*)d_in[8];
    const float* b_sin  = (const float*)d_in[9];
    const float* W_cos  = (const float*)d_in[10];
    const float* b_cos  = (const float*)d_in[11];
    float* out = (float*)d_out;

    const int N = in_sizes[0] / F_IN;          // 200000
    const int E = in_sizes[1] / 2;             // 6400000
    const int L = in_sizes[4] / (DIM * DIM);   // 4
    const int* src = edge;
    const int* dst = edge + E;

    // workspace layout
    char* ws = (char*)d_ws;
    float* dinv  = (float*)ws;                                   // N floats (deg in-place)
    float* y     = (float*)(ws + (size_t)N * 4);                 // N*16
    float* agg   = (float*)(ws + (size_t)N * 4 + (size_t)N * DIM * 4);
    float* h     = (float*)(ws + (size_t)N * 4 + 2 * (size_t)N * DIM * 4);
    float* bnsum = (float*)(ws + (size_t)N * 4 + 3 * (size_t)N * DIM * 4); // 32 floats per layer

    const int tot = N * DIM;

    hipMemsetAsync(dinv, 0, (size_t)N * 4, stream);
    hipMemsetAsync(bnsum, 0, 32 * 4 * (size_t)L, stream);
    deg_kernel<<<(E + 255) / 256, 256, 0, stream>>>(dst, (unsigned*)dinv, E);
    dinv_kernel<<<(N + 255) / 256, 256, 0, stream>>>(dinv, N);

    auto conv = [&](const float* hin, const float* W, const float* bias, float* outbuf,
                    int fin, int mode, float* bns) {
        if (fin == F_IN)
            xw64_kernel<<<(tot + 255) / 256, 256, 0, stream>>>(hin, W, dinv, y, N);
        else
            xw16_kernel<<<(tot + 255) / 256, 256, 0, stream>>>(hin, W, dinv, y, N);
        hipMemsetAsync(agg, 0, (size_t)tot * 4, stream);
        scatter_kernel<<<(E * DIM + 255) / 256, 256, 0, stream>>>(src, dst, y, agg, E);
        finalize_kernel<<<1024, 256, 0, stream>>>(agg, y, dinv, bias, outbuf, bns, N, mode);
    };

    // input layer: 64 -> 16, no BN/ReLU
    conv(x, W_in, b_in, h, F_IN, 0, nullptr);

    // hidden layers: conv -> BN -> ReLU
    for (int l = 0; l < L; ++l) {
        conv(h, Ws + l * DIM * DIM, bs + l * DIM, y /*in-place*/, DIM, 1, bnsum + 32 * l);
        bn_relu_kernel<<<(tot + 255) / 256, 256, 0, stream>>>(
            y, bnsum + 32 * l, gammas + l * DIM, betas + l * DIM, h, N);
    }

    // output heads: conv -> ReLU, straight into d_out
    conv(h, W_sin, b_sin, out, DIM, 2, nullptr);
    conv(h, W_cos, b_cos, out + tot, DIM, 2, nullptr);
}

// Round 2
// 2408.113 us; speedup vs baseline: 1.2156x; 1.2156x over previous
//
#include <hip/hip_runtime.h>

// RNAGNN: 7× GCNConv + 4× BatchNorm/ReLU on N=200k nodes, E=6.4M edges.
// Round 2: CSR-gather formulation (no float atomics).
//   y = dinv ⊙ (h @ W)
//   out[d] = dinv[d] * ( y[d] + Σ_{e: dst=d} y[src_e] ) + b
// CSR (grouped by dst) built once per call: histogram -> block scan -> cursor fill.

#define DIM 16
#define F_IN 64

// ---------------- degree + dinv ----------------

__global__ void deg_kernel(const int* __restrict__ dst, int* __restrict__ deg, int E) {
    int e = blockIdx.x * blockDim.x + threadIdx.x;
    if (e < E) atomicAdd(&deg[dst[e]], 1);
}

__global__ void dinv_kernel(const int* __restrict__ deg, float* __restrict__ dinv, int n) {
    int i = blockIdx.x * blockDim.x + threadIdx.x;
    if (i < n) dinv[i] = rsqrtf((float)(deg[i] + 1));  // +1 = self loop
}

// ---------------- exclusive scan over deg (N <= 256*1024) ----------------

__global__ void blk_reduce_kernel(const int* __restrict__ deg, int* __restrict__ partial, int n) {
    __shared__ int sd[256];
    int t = threadIdx.x, base = blockIdx.x * 1024;
    int s = 0;
#pragma unroll
    for (int j = 0; j < 4; ++j) {
        int i = base + t * 4 + j;
        if (i < n) s += deg[i];
    }
    sd[t] = s;
    __syncthreads();
    for (int st = 128; st > 0; st >>= 1) {
        if (t < st) sd[t] += sd[t + st];
        __syncthreads();
    }
    if (t == 0) partial[blockIdx.x] = sd[0];
}

__global__ void scan_partials_kernel(int* __restrict__ partial, int nb) {
    __shared__ int sd[256];
    int t = threadIdx.x;
    sd[t] = (t < nb) ? partial[t] : 0;
    __syncthreads();
    for (int off = 1; off < 256; off <<= 1) {
        int v = (t >= off) ? sd[t - off] : 0;
        __syncthreads();
        sd[t] += v;
        __syncthreads();
    }
    if (t < nb) partial[t] = (t > 0) ? sd[t - 1] : 0;   // exclusive
}

__global__ void scan_final_kernel(const int* __restrict__ deg, const int* __restrict__ partial,
                                  int* __restrict__ rowptr, int* __restrict__ cursor, int n) {
    __shared__ int sd[256];
    int t = threadIdx.x, base = blockIdx.x * 1024;
    int v[4];
    int s = 0;
#pragma unroll
    for (int j = 0; j < 4; ++j) {
        int i = base + t * 4 + j;
        v[j] = (i < n) ? deg[i] : 0;
        s += v[j];
    }
    sd[t] = s;
    __syncthreads();
    for (int off = 1; off < 256; off <<= 1) {
        int u = (t >= off) ? sd[t - off] : 0;
        __syncthreads();
        sd[t] += u;
        __syncthreads();
    }
    int excl = ((t > 0) ? sd[t - 1] : 0) + partial[blockIdx.x];
#pragma unroll
    for (int j = 0; j < 4; ++j) {
        int i = base + t * 4 + j;
        if (i < n) { rowptr[i] = excl; cursor[i] = excl; excl += v[j]; }
    }
}

__global__ void fill_kernel(const int* __restrict__ src, const int* __restrict__ dst,
                            int* __restrict__ cursor, int* __restrict__ col, int E) {
    int e = blockIdx.x * blockDim.x + threadIdx.x;
    if (e < E) {
        int pos = atomicAdd(&cursor[dst[e]], 1);
        col[pos] = src[e];
    }
}

// ---------------- y = dinv * (x @ W) ----------------

__global__ void xw64_kernel(const float* __restrict__ x, const float* __restrict__ W,
                            const float* __restrict__ dinv, float* __restrict__ y, int n) {
    __shared__ float sW[F_IN * DIM];
    int t = threadIdx.x;
    for (int i = t; i < F_IN * DIM; i += blockDim.x) sW[i] = W[i];
    __syncthreads();
    int idx = blockIdx.x * blockDim.x + t;
    if (idx >= n * DIM) return;
    int i = idx >> 4, f = idx & 15;
    const float* xr = x + (size_t)i * F_IN;
    float acc = 0.f;
#pragma unroll
    for (int k = 0; k < F_IN; ++k) acc += xr[k] * sW[k * DIM + f];
    y[idx] = dinv[i] * acc;
}

__global__ void xw16_kernel(const float* __restrict__ h, const float* __restrict__ W,
                            const float* __restrict__ dinv, float* __restrict__ y, int n) {
    __shared__ float sW[DIM * DIM];
    int t = threadIdx.x;
    if (t < DIM * DIM) sW[t] = W[t];
    __syncthreads();
    int idx = blockIdx.x * blockDim.x + t;
    if (idx >= n * DIM) return;
    int i = idx >> 4, f = idx & 15;
    const float* hr = h + (size_t)i * DIM;
    float acc = 0.f;
#pragma unroll
    for (int k = 0; k < DIM; ++k) acc += hr[k] * sW[k * DIM + f];
    y[idx] = dinv[i] * acc;
}

// ---------------- gather + finalize (fused) ----------------
// 4 threads per node; thread q owns features [q*4, q*4+4).
// mode 0: plain write; mode 1: write + BN partial sums; mode 2: ReLU write.

__global__ void gather_kernel(const int* __restrict__ rowptr, const int* __restrict__ deg,
                              const int* __restrict__ col, const float4* __restrict__ y4,
                              const float* __restrict__ dinv, const float4* __restrict__ b4,
                              float4* __restrict__ out4, float* __restrict__ bnsum,
                              int n, int mode) {
    __shared__ float s1[256 * 4];
    __shared__ float s2[256 * 4];
    int idx = blockIdx.x * blockDim.x + threadIdx.x;
    int i = idx >> 2, q = idx & 3;
    float4 sum = make_float4(0.f, 0.f, 0.f, 0.f);
    float4 sumsq = make_float4(0.f, 0.f, 0.f, 0.f);
    if (i < n) {
        int start = rowptr[i], len = deg[i];
        float4 acc = y4[(size_t)i * 4 + q];          // self loop
        for (int k = 0; k < len; ++k) {
            int s = col[start + k];
            float4 v = y4[(size_t)s * 4 + q];
            acc.x += v.x; acc.y += v.y; acc.z += v.z; acc.w += v.w;
        }
        float di = dinv[i];
        float4 bb = b4[q];
        float4 r;
        r.x = di * acc.x + bb.x;
        r.y = di * acc.y + bb.y;
        r.z = di * acc.z + bb.z;
        r.w = di * acc.w + bb.w;
        if (mode == 2) {
            r.x = fmaxf(r.x, 0.f); r.y = fmaxf(r.y, 0.f);
            r.z = fmaxf(r.z, 0.f); r.w = fmaxf(r.w, 0.f);
        }
        out4[(size_t)i * 4 + q] = r;
        if (mode == 1) {
            sum = r;
            sumsq.x = r.x * r.x; sumsq.y = r.y * r.y;
            sumsq.z = r.z * r.z; sumsq.w = r.w * r.w;
        }
    }
    if (mode == 1) {
        int t = threadIdx.x;
        s1[t * 4 + 0] = sum.x;   s1[t * 4 + 1] = sum.y;
        s1[t * 4 + 2] = sum.z;   s1[t * 4 + 3] = sum.w;
        s2[t * 4 + 0] = sumsq.x; s2[t * 4 + 1] = sumsq.y;
        s2[t * 4 + 2] = sumsq.z; s2[t * 4 + 3] = sumsq.w;
        __syncthreads();
        for (int st = 128; st >= 4; st >>= 1) {      // strides all %4==0: feature-preserving
            if (t < st) {
#pragma unroll
                for (int j = 0; j < 4; ++j) {
                    s1[t * 4 + j] += s1[(t + st) * 4 + j];
                    s2[t * 4 + j] += s2[(t + st) * 4 + j];
                }
            }
            __syncthreads();
        }
        if (t < 4) {
#pragma unroll
            for (int j = 0; j < 4; ++j) {
                atomicAdd(&bnsum[t * 4 + j], s1[t * 4 + j]);
                atomicAdd(&bnsum[16 + t * 4 + j], s2[t * 4 + j]);
            }
        }
    }
}

// ---------------- BN apply + ReLU ----------------

__global__ void bn_relu_kernel(const float4* __restrict__ hp, const float* __restrict__ bnsum,
                               const float* __restrict__ gamma, const float* __restrict__ beta,
                               float4* __restrict__ h, int n) {
    int idx = blockIdx.x * blockDim.x + threadIdx.x;
    if (idx >= n * 4) return;
    int q = idx & 3;
    float invN = 1.f / (float)n;
    float4 v = hp[idx];
    float vv[4] = { v.x, v.y, v.z, v.w };
    float rr[4];
#pragma unroll
    for (int j = 0; j < 4; ++j) {
        int f = q * 4 + j;
        float mean = bnsum[f] * invN;
        float var = fmaxf(bnsum[16 + f] * invN - mean * mean, 0.f);
        rr[j] = fmaxf(gamma[f] * (vv[j] - mean) * rsqrtf(var + 1e-5f) + beta[f], 0.f);
    }
    h[idx] = make_float4(rr[0], rr[1], rr[2], rr[3]);
}

// ---------------- launcher ----------------

extern "C" void kernel_launch(void* const* d_in, const int* in_sizes, int n_in,
                              void* d_out, int out_size, void* d_ws, size_t ws_size,
                              hipStream_t stream) {
    (void)n_in; (void)out_size; (void)ws_size;
    const float* x      = (const float*)d_in[0];
    const int*   edge   = (const int*)d_in[1];
    const float* W_in   = (const float*)d_in[2];
    const float* b_in   = (const float*)d_in[3];
    const float* Ws     = (const float*)d_in[4];
    const float* bs     = (const float*)d_in[5];
    const float* gammas = (const float*)d_in[6];
    const float* betas  = (const float*)d_in[7];
    const float* W_sin  = (const float*)d_in[8];
    const float* b_sin  = (const float*)d_in[9];
    const float* W_cos  = (const float*)d_in[10];
    const float* b_cos  = (const float*)d_in[11];
    float* out = (float*)d_out;

    const int N = in_sizes[0] / F_IN;          // 200000
    const int E = in_sizes[1] / 2;             // 6400000
    const int L = in_sizes[4] / (DIM * DIM);   // 4
    const int* src = edge;
    const int* dst = edge + E;

    // workspace layout (all 16B aligned)
    char* ws = (char*)d_ws;
    size_t off = 0;
    auto alloc = [&](size_t bytes) { char* p = ws + off; off += (bytes + 15) & ~size_t(15); return p; };
    int*   deg     = (int*)alloc((size_t)N * 4);
    float* dinv    = (float*)alloc((size_t)N * 4);
    int*   rowptr  = (int*)alloc((size_t)N * 4);
    int*   cursor  = (int*)alloc((size_t)N * 4);
    int*   col     = (int*)alloc((size_t)E * 4);
    int*   partial = (int*)alloc(256 * 4);
    float* y       = (float*)alloc((size_t)N * DIM * 4);
    float* h       = (float*)alloc((size_t)N * DIM * 4);
    float* hp      = (float*)alloc((size_t)N * DIM * 4);
    float* bnsum   = (float*)alloc(32 * 4 * (size_t)L);

    const int tot = N * DIM;
    const int n4  = N * 4;
    const int NB  = (N + 1023) / 1024;         // 196 <= 256

    hipMemsetAsync(deg, 0, (size_t)N * 4, stream);
    hipMemsetAsync(bnsum, 0, 32 * 4 * (size_t)L, stream);

    deg_kernel<<<(E + 255) / 256, 256, 0, stream>>>(dst, deg, E);
    dinv_kernel<<<(N + 255) / 256, 256, 0, stream>>>(deg, dinv, N);
    blk_reduce_kernel<<<NB, 256, 0, stream>>>(deg, partial, N);
    scan_partials_kernel<<<1, 256, 0, stream>>>(partial, NB);
    scan_final_kernel<<<NB, 256, 0, stream>>>(deg, partial, rowptr, cursor, N);
    fill_kernel<<<(E + 255) / 256, 256, 0, stream>>>(src, dst, cursor, col, E);

    auto conv = [&](const float* hin, const float* W, const float* bias, float* outbuf,
                    int fin, int mode, float* bns) {
        if (fin == F_IN)
            xw64_kernel<<<(tot + 255) / 256, 256, 0, stream>>>(hin, W, dinv, y, N);
        else
            xw16_kernel<<<(tot + 255) / 256, 256, 0, stream>>>(hin, W, dinv, y, N);
        gather_kernel<<<(n4 + 255) / 256, 256, 0, stream>>>(
            rowptr, deg, col, (const float4*)y, dinv, (const float4*)bias,
            (float4*)outbuf, bns, N, mode);
    };

    // input layer: 64 -> 16, no BN/ReLU
    conv(x, W_in, b_in, h, F_IN, 0, nullptr);

    // hidden layers: conv -> BN -> ReLU
    for (int l = 0; l < L; ++l) {
        conv(h, Ws + l * DIM * DIM, bs + l * DIM, hp, DIM, 1, bnsum + 32 * l);
        bn_relu_kernel<<<(n4 + 255) / 256, 256, 0, stream>>>(
            (const float4*)hp, bnsum + 32 * l, gammas + l * DIM, betas + l * DIM,
            (float4*)h, N);
    }

    // output heads: conv -> ReLU, straight into d_out
    conv(h, W_sin, b_sin, out, DIM, 2, nullptr);
    conv(h, W_cos, b_cos, out + tot, DIM, 2, nullptr);
}